// Round 13
// baseline (693.929 us; speedup 1.0000x reference)
//
#include <hip/hip_runtime.h>
#include <hip/hip_fp8.h>

#define NCLS 1000
#define DIM 256
#define GCAP 500
#define NT16 64                    // 64 tiles of 16 cols over 1024 padded cols
#define SCLF 20.609930f            // 1/(0.07*ln2)
#define CP 23.0f
#define CPLN2 15.94238515f         // 23*ln2
#define LN2 0.69314718056f
#define PADC 2.86102294921875e-06f // 24 * 2^-23 (pad-column contribution)

typedef __attribute__((ext_vector_type(4))) float f32x4;
typedef long long i64;

#if defined(__has_builtin) && __has_builtin(__builtin_amdgcn_cvt_pk_fp8_f32)
#define CVTPK(a, b, old, hi) __builtin_amdgcn_cvt_pk_fp8_f32((a), (b), (old), (hi))
#else
__device__ __forceinline__ unsigned cvtpk_sw(float a, float b, unsigned old, bool hi) {
  unsigned lo8 = __hip_cvt_float_to_fp8(a, __HIP_SATFINITE, __HIP_E4M3);
  unsigned hi8 = __hip_cvt_float_to_fp8(b, __HIP_SATFINITE, __HIP_E4M3);
  unsigned pk = lo8 | (hi8 << 8);
  return hi ? ((old & 0xffffu) | (pk << 16)) : ((old & 0xffff0000u) | pk);
}
#define CVTPK(a, b, old, hi) cvtpk_sw((a), (b), (old), (hi))
#endif

__device__ __forceinline__ float fexp2(float x) {
#if __has_builtin(__builtin_amdgcn_exp2f)
  return __builtin_amdgcn_exp2f(x);
#else
  return exp2f(x);
#endif
}
__device__ __forceinline__ void gload_lds16(const void* g, void* l) {
  __builtin_amdgcn_global_load_lds(
      (const __attribute__((address_space(1))) unsigned int*)g,
      (__attribute__((address_space(3))) unsigned int*)l, 16, 0, 0);
}

// ---------------- K0: scatter rows into per-class lists ------------------------
__global__ __launch_bounds__(256) void scatter_kernel(
    const int* __restrict__ sl, const int* __restrict__ tl, int N,
    int* __restrict__ gcnt, int* __restrict__ glist) {
  const int i = blockIdx.x * 256 + threadIdx.x;
  if (i >= 2 * N) return;
  const int side = (i >= N) ? 1 : 0;
  const int r = i - side * N;
  const int c = (side ? tl : sl)[r];
  const int bin = side * NCLS + c;
  const int slot = atomicAdd(gcnt + bin, 1);
  if (slot < GCAP) glist[(size_t)bin * GCAP + slot] = r;
}

// ---------------- K1: per-class gather + mean + normalize ----------------------
__global__ __launch_bounds__(256) void proto_kernel(
    const float* __restrict__ sf, const float* __restrict__ tf,
    const int* __restrict__ gcnt, const int* __restrict__ glist,
    float* __restrict__ mean_out, float* __restrict__ spn, float* __restrict__ tpn,
    unsigned char* __restrict__ pbf8) {
  const int bid = blockIdx.x;
  const int side = (bid >= NCLS) ? 1 : 0;
  const int c = bid - side * NCLS;
  const float* feats = side ? tf : sf;
  const int* list = glist + (size_t)bid * GCAP;
  const int m = min(gcnt[bid], GCAP);
  const int t = threadIdx.x;
  __shared__ float s_red[4];

  float a0 = 0.f, a1 = 0.f, a2 = 0.f, a3 = 0.f, a4 = 0.f, a5 = 0.f, a6 = 0.f, a7 = 0.f;
  int i = 0;
  for (; i + 8 <= m; i += 8) {
    a0 += feats[(size_t)list[i + 0] * DIM + t];
    a1 += feats[(size_t)list[i + 1] * DIM + t];
    a2 += feats[(size_t)list[i + 2] * DIM + t];
    a3 += feats[(size_t)list[i + 3] * DIM + t];
    a4 += feats[(size_t)list[i + 4] * DIM + t];
    a5 += feats[(size_t)list[i + 5] * DIM + t];
    a6 += feats[(size_t)list[i + 6] * DIM + t];
    a7 += feats[(size_t)list[i + 7] * DIM + t];
  }
  for (; i < m; i++) a0 += feats[(size_t)list[i] * DIM + t];
  const float sum = ((a0 + a1) + (a2 + a3)) + ((a4 + a5) + (a6 + a7));
  const float mean = sum / fmaxf((float)m, 1.0f);
  if (!side) mean_out[(size_t)c * DIM + t] = mean;

  float ss = mean * mean;
  #pragma unroll
  for (int o = 1; o < 64; o <<= 1) ss += __shfl_xor(ss, o);
  if ((t & 63) == 0) s_red[t >> 6] = ss;
  __syncthreads();
  const float tot = s_red[0] + s_red[1] + s_red[2] + s_red[3];
  const float innv = 1.0f / fmaxf(sqrtf(tot), 1e-12f);
  const float p = mean * innv;
  (side ? tpn : spn)[(size_t)c * DIM + t] = p;
  if (!side) {
    // fp8 tiled layout: [c>>4][kf2=t>>6][lg=(t>>3)&3][c&15][odd=(t>>5)&1][e=t&7]
    size_t off = (size_t)(c >> 4) * 4096 + (size_t)(t >> 6) * 1024
               + (size_t)((t >> 3) & 3) * 256 + (size_t)(c & 15) * 16
               + (size_t)((t >> 5) & 1) * 8 + (t & 7);
    unsigned q = CVTPK(p, p, 0u, false);
    pbf8[off] = (unsigned char)(q & 0xffu);
  }
}

// ---------------- K2: structure matrices + struct loss (fp32, 64x64 tiles) -----
__global__ __launch_bounds__(256) void struct_kernel(
    const float* __restrict__ spn, const float* __restrict__ tpn,
    float* __restrict__ out_struct, float* __restrict__ acc) {
  __shared__ float Sa[16][68], Sb[16][68], Ta[16][68], Tb[16][68];
  __shared__ float red[256];
  const int t = threadIdx.x;
  const int tx = t & 15, ty = t >> 4;
  const int i0 = blockIdx.y * 64, j0 = blockIdx.x * 64;
  float cs[4][4], cg[4][4];
  #pragma unroll
  for (int a = 0; a < 4; a++)
    #pragma unroll
    for (int b = 0; b < 4; b++) { cs[a][b] = 0.f; cg[a][b] = 0.f; }

  const int srow = t >> 2;
  const int skq = (t & 3) * 4;
  for (int k0 = 0; k0 < DIM; k0 += 16) {
    __syncthreads();
    {
      float4 z = make_float4(0.f, 0.f, 0.f, 0.f);
      int ra = i0 + srow, rb = j0 + srow;
      float4 va = (ra < NCLS) ? *(const float4*)(spn + (size_t)ra * DIM + k0 + skq) : z;
      float4 vb = (rb < NCLS) ? *(const float4*)(spn + (size_t)rb * DIM + k0 + skq) : z;
      float4 wa = (ra < NCLS) ? *(const float4*)(tpn + (size_t)ra * DIM + k0 + skq) : z;
      float4 wb = (rb < NCLS) ? *(const float4*)(tpn + (size_t)rb * DIM + k0 + skq) : z;
      Sa[skq+0][srow]=va.x; Sa[skq+1][srow]=va.y; Sa[skq+2][srow]=va.z; Sa[skq+3][srow]=va.w;
      Sb[skq+0][srow]=vb.x; Sb[skq+1][srow]=vb.y; Sb[skq+2][srow]=vb.z; Sb[skq+3][srow]=vb.w;
      Ta[skq+0][srow]=wa.x; Ta[skq+1][srow]=wa.y; Ta[skq+2][srow]=wa.z; Ta[skq+3][srow]=wa.w;
      Tb[skq+0][srow]=wb.x; Tb[skq+1][srow]=wb.y; Tb[skq+2][srow]=wb.z; Tb[skq+3][srow]=wb.w;
    }
    __syncthreads();
    #pragma unroll
    for (int k = 0; k < 16; k++) {
      float a[4], b[4], c[4], d[4];
      *(float4*)a = *(const float4*)&Sa[k][ty * 4];
      *(float4*)b = *(const float4*)&Sb[k][tx * 4];
      *(float4*)c = *(const float4*)&Ta[k][ty * 4];
      *(float4*)d = *(const float4*)&Tb[k][tx * 4];
      #pragma unroll
      for (int ii = 0; ii < 4; ii++)
        #pragma unroll
        for (int jj = 0; jj < 4; jj++) {
          cs[ii][jj] = fmaf(a[ii], b[jj], cs[ii][jj]);
          cg[ii][jj] = fmaf(c[ii], d[jj], cg[ii][jj]);
        }
    }
  }
  float d2 = 0.f;
  #pragma unroll
  for (int ii = 0; ii < 4; ii++) {
    int gi = i0 + ty * 4 + ii;
    if (gi < NCLS) {
      #pragma unroll
      for (int jj = 0; jj < 4; jj++) {
        int gj = j0 + tx * 4 + jj;
        if (gj < NCLS) {
          out_struct[(size_t)gi * NCLS + gj] = cs[ii][jj];
          float df = cs[ii][jj] - cg[ii][jj];
          d2 += df * df;
        }
      }
    }
  }
  red[t] = d2;
  __syncthreads();
  for (int o = 128; o > 0; o >>= 1) { if (t < o) red[t] += red[t + o]; __syncthreads(); }
  if (t == 0) atomicAdd(acc, red[0]);
}

// ------- K3: contrastive loss — fp8 MFMA, ring-4 LDS, m201-style pipeline ------
// Phase h: STAGE(h+3) | lgkm0 (b=tile h ready, read last phase) | 16 MFMA |
//          vmcnt(2) | barrier | ds_read(h+1)->b | exp(h).  vmcnt never 0 mid-loop.
__global__ __launch_bounds__(256, 3) void contrast_kernel(
    const float* __restrict__ feats, const int* __restrict__ labels,
    const float* __restrict__ pn, const unsigned char* __restrict__ pbf8,
    float* __restrict__ acc_out, int N) {
  __shared__ __align__(16) unsigned char Bt[4][4096];  // ring-4 of 4KB fp8 tiles
  __shared__ float red[256];
  const int t = threadIdx.x;
  const int lane = t & 63;
  const int lx = lane & 15, lg = lane >> 4;
  const int row0 = blockIdx.x * 128 + (t >> 6) * 32;
  const float4 z4 = make_float4(0.f, 0.f, 0.f, 0.f);

  i64 af[2][8];          // 32 rows/wave, raw feats in e4m3
  float sclF[2][4];      // (1/(T*ln2))/||f|| per owned row
  float sSt[2][4];
  float wpre = 0.f;      // per-lane partial: (label fp32 dot) * sw

  #pragma unroll
  for (int rf = 0; rf < 2; rf++) {
    const int r = row0 + rf * 16 + lx;
    const bool v = r < N;
    const float* rp = feats + (size_t)r * DIM + (lg << 3);
    const int lb = v ? labels[r] : 0;
    const float* pp = pn + (size_t)lb * DIM + (lg << 3);
    float n2 = 0.f, pl = 0.f;
    #pragma unroll
    for (int kf = 0; kf < 8; kf++) {
      float4 x  = v ? *(const float4*)(rp + kf * 32)     : z4;
      float4 y  = v ? *(const float4*)(rp + kf * 32 + 4) : z4;
      float4 px = v ? *(const float4*)(pp + kf * 32)     : z4;
      float4 py = v ? *(const float4*)(pp + kf * 32 + 4) : z4;
      n2 += x.x*x.x + x.y*x.y + x.z*x.z + x.w*x.w
          + y.x*y.x + y.y*y.y + y.z*y.z + y.w*y.w;
      pl += x.x*px.x + x.y*px.y + x.z*px.z + x.w*px.w
          + y.x*py.x + y.y*py.y + y.z*py.z + y.w*py.w;
      unsigned w0 = CVTPK(x.x, x.y, 0u, false);
      w0 = CVTPK(x.z, x.w, w0, true);
      unsigned w1 = CVTPK(y.x, y.y, 0u, false);
      w1 = CVTPK(y.z, y.w, w1, true);
      af[rf][kf] = (i64)(((unsigned long long)w1 << 32) | (unsigned long long)w0);
    }
    n2 += __shfl_xor(n2, 16);
    n2 += __shfl_xor(n2, 32);
    const float sw = SCLF / fmaxf(sqrtf(n2), 1e-12f);
    wpre += pl * sw;
    #pragma unroll
    for (int reg = 0; reg < 4; reg++) {
      sclF[rf][reg] = __shfl(sw, (lg << 2) | reg);
      sSt[rf][reg] = 0.f;
    }
  }

  // stage tile h_ (4KB): one gload_lds16 per thread (block-linear)
  #define STAGE13(h_, s_)                                                       \
    {                                                                           \
      const unsigned char* g0 = pbf8 + ((size_t)(h_) << 12) + (t << 4);         \
      gload_lds16(g0, &Bt[s_][t << 4]);                                         \
    }

  int4 b[4];   // read-ahead register tile: b[kf2] = 16B at kf2*1024
  #define DSREAD13(s_)                                                          \
    {                                                                           \
      const unsigned char* bb = &Bt[s_][(lg << 8) + (lx << 4)];                 \
      b[0] = *(const int4*)(bb);                                                \
      b[1] = *(const int4*)(bb + 1024);                                         \
      b[2] = *(const int4*)(bb + 2048);                                         \
      b[3] = *(const int4*)(bb + 3072);                                         \
    }

  STAGE13(0, 0);
  STAGE13(1, 1);
  STAGE13(2, 2);
  asm volatile("s_waitcnt vmcnt(2)" ::: "memory");   // tile 0 retired (1,2 in flight)
  __builtin_amdgcn_s_barrier();                      // tile 0 published
  __builtin_amdgcn_sched_barrier(0);
  DSREAD13(0);

  for (int h = 0; h < NT16; h++) {
    if (h < NT16 - 3) STAGE13(h + 3, (h + 3) & 3);

    asm volatile("s_waitcnt lgkmcnt(0)" ::: "memory");  // b = tile h complete
    __builtin_amdgcn_sched_barrier(0);                  // rule 18: pin MFMA below

    f32x4 d0 = {0.f, 0.f, 0.f, 0.f};
    f32x4 d1 = {0.f, 0.f, 0.f, 0.f};
    __builtin_amdgcn_s_setprio(1);
    #pragma unroll
    for (int q = 0; q < 4; q++) {
      i64 b0 = ((const i64*)&b[q])[0];
      i64 b1 = ((const i64*)&b[q])[1];
      d0 = __builtin_amdgcn_mfma_f32_16x16x32_fp8_fp8(af[0][2*q],   b0, d0, 0, 0, 0);
      d1 = __builtin_amdgcn_mfma_f32_16x16x32_fp8_fp8(af[1][2*q],   b0, d1, 0, 0, 0);
      d0 = __builtin_amdgcn_mfma_f32_16x16x32_fp8_fp8(af[0][2*q+1], b1, d0, 0, 0, 0);
      d1 = __builtin_amdgcn_mfma_f32_16x16x32_fp8_fp8(af[1][2*q+1], b1, d1, 0, 0, 0);
    }
    __builtin_amdgcn_s_setprio(0);

    if (h < NT16 - 1) {
      // counted drain: tile h+1 globally retired, deeper prefetches stay in flight
      if (h < NT16 - 3)       { asm volatile("s_waitcnt vmcnt(2)" ::: "memory"); }
      else if (h == NT16 - 3) { asm volatile("s_waitcnt vmcnt(1)" ::: "memory"); }
      else                    { asm volatile("s_waitcnt vmcnt(0)" ::: "memory"); }
      __builtin_amdgcn_s_barrier();
      __builtin_amdgcn_sched_barrier(0);               // pin ds_read below barrier
      DSREAD13((h + 1) & 3);
      // ds_read latency hides under the exp tail + next phase's STAGE/lgkm wait
    }

    #pragma unroll
    for (int reg = 0; reg < 4; reg++) {
      sSt[0][reg] += fexp2(fmaf(d0[reg], sclF[0][reg], -CP));
      sSt[1][reg] += fexp2(fmaf(d1[reg], sclF[1][reg], -CP));
    }
  }

  float wl = 0.f;
  #pragma unroll
  for (int rf = 0; rf < 2; rf++)
    #pragma unroll
    for (int reg = 0; reg < 4; reg++) {
      float s = sSt[rf][reg];
      #pragma unroll
      for (int o = 1; o < 16; o <<= 1) s += __shfl_xor(s, o);
      const int row = row0 + rf * 16 + (lg << 2) + reg;
      if (lx == 0 && row < N) wl += logf(s - PADC) + CPLN2;
    }

  red[t] = wl - wpre * LN2;
  __syncthreads();
  for (int o = 128; o > 0; o >>= 1) { if (t < o) red[t] += red[t + o]; __syncthreads(); }
  if (t == 0) atomicAdd(acc_out, red[0]);
}

// ---------------- K4: scalars ---------------------------------------------------
__global__ void final_kernel(const float* __restrict__ acc, float* __restrict__ out, int N) {
  out[0] = acc[0] * (1.0f / (float)(NCLS * NCLS));
  out[1] = acc[1] / (float)N;
}

extern "C" void kernel_launch(void* const* d_in, const int* in_sizes, int n_in,
                              void* d_out, int out_size, void* d_ws, size_t ws_size,
                              hipStream_t stream) {
  const float* src_feats  = (const float*)d_in[0];
  const int*   src_labels = (const int*)d_in[1];
  const float* tgt_feats  = (const float*)d_in[2];
  const int*   tgt_labels = (const int*)d_in[3];
  const int N = in_sizes[0] / DIM;

  // ws layout (floats):
  // [0,16)           acc: [0]=struct sq-sum, [1]=contrast sum
  // [16,256016)      src_pn
  // [256016,512016)  tgt_pn
  // [512016,577552)  pbf8: 64 tiles x 4096 bytes (fp8 e4m3, 1024 padded cols)
  // [643088,645088)  gcnt: 2000 ints
  float* ws = (float*)d_ws;
  float* acc    = ws;
  float* src_pn = ws + 16;
  float* tgt_pn = ws + 256016;
  unsigned char* pbf8 = (unsigned char*)(ws + 512016);
  int* gcnt = (int*)(ws + 643088);

  float* out_f      = (float*)d_out;
  float* out_protos = out_f + 2;
  float* out_struct = out_f + 2 + NCLS * DIM;
  // glist borrows the out_struct region (1M ints); struct_kernel overwrites it later
  int* glist = (int*)out_struct;

  hipMemsetAsync(acc, 0, 2 * sizeof(float), stream);
  hipMemsetAsync(gcnt, 0, 2 * NCLS * sizeof(int), stream);
  hipMemsetAsync(pbf8 + 62 * 4096, 0, 2 * 4096, stream);

  int sblocks = (2 * N + 255) / 256;
  scatter_kernel<<<sblocks, 256, 0, stream>>>(src_labels, tgt_labels, N, gcnt, glist);

  proto_kernel<<<2 * NCLS, 256, 0, stream>>>(src_feats, tgt_feats, gcnt, glist,
                                             out_protos, src_pn, tgt_pn, pbf8);

  dim3 sgrid(16, 16);
  struct_kernel<<<sgrid, 256, 0, stream>>>(src_pn, tgt_pn, out_struct, acc);

  int cblocks = (N + 127) / 128;
  contrast_kernel<<<cblocks, 256, 0, stream>>>(src_feats, src_labels, src_pn, pbf8,
                                               acc + 1, N);

  final_kernel<<<1, 1, 0, stream>>>(acc, out_f, N);
}

// Round 14
// 409.291 us; speedup vs baseline: 1.6954x; 1.6954x over previous
//
#include <hip/hip_runtime.h>
#include <hip/hip_fp8.h>

#define NCLS 1000
#define DIM 256
#define GCAP 500
#define NT16 64                    // 64 tiles of 16 cols over 1024 padded cols
#define SCLF 20.609930f            // 1/(0.07*ln2)
#define CP 23.0f
#define CPLN2 15.94238515f         // 23*ln2
#define LN2 0.69314718056f
#define PADC 2.86102294921875e-06f // 24 * 2^-23 (pad-column contribution)

typedef __attribute__((ext_vector_type(4))) float f32x4;
typedef long long i64;
typedef unsigned long long u64;

#if defined(__has_builtin) && __has_builtin(__builtin_amdgcn_cvt_pk_fp8_f32)
#define CVTPK(a, b, old, hi) __builtin_amdgcn_cvt_pk_fp8_f32((a), (b), (old), (hi))
#else
__device__ __forceinline__ unsigned cvtpk_sw(float a, float b, unsigned old, bool hi) {
  unsigned lo8 = __hip_cvt_float_to_fp8(a, __HIP_SATFINITE, __HIP_E4M3);
  unsigned hi8 = __hip_cvt_float_to_fp8(b, __HIP_SATFINITE, __HIP_E4M3);
  unsigned pk = lo8 | (hi8 << 8);
  return hi ? ((old & 0xffffu) | (pk << 16)) : ((old & 0xffff0000u) | pk);
}
#define CVTPK(a, b, old, hi) cvtpk_sw((a), (b), (old), (hi))
#endif

__device__ __forceinline__ float fexp2(float x) {
#if __has_builtin(__builtin_amdgcn_exp2f)
  return __builtin_amdgcn_exp2f(x);
#else
  return exp2f(x);
#endif
}
__device__ __forceinline__ void gload_lds16(const void* g, void* l) {
  __builtin_amdgcn_global_load_lds(
      (const __attribute__((address_space(1))) unsigned int*)g,
      (__attribute__((address_space(3))) unsigned int*)l, 16, 0, 0);
}

// ---------------- K0: scatter rows into per-class lists ------------------------
__global__ __launch_bounds__(256) void scatter_kernel(
    const int* __restrict__ sl, const int* __restrict__ tl, int N,
    int* __restrict__ gcnt, int* __restrict__ glist) {
  const int i = blockIdx.x * 256 + threadIdx.x;
  if (i >= 2 * N) return;
  const int side = (i >= N) ? 1 : 0;
  const int r = i - side * N;
  const int c = (side ? tl : sl)[r];
  const int bin = side * NCLS + c;
  const int slot = atomicAdd(gcnt + bin, 1);
  if (slot < GCAP) glist[(size_t)bin * GCAP + slot] = r;
}

// ---------------- K1: per-class gather + mean + normalize ----------------------
__global__ __launch_bounds__(256) void proto_kernel(
    const float* __restrict__ sf, const float* __restrict__ tf,
    const int* __restrict__ gcnt, const int* __restrict__ glist,
    float* __restrict__ mean_out, float* __restrict__ spn, float* __restrict__ tpn,
    unsigned char* __restrict__ pbf8) {
  const int bid = blockIdx.x;
  const int side = (bid >= NCLS) ? 1 : 0;
  const int c = bid - side * NCLS;
  const float* feats = side ? tf : sf;
  const int* list = glist + (size_t)bid * GCAP;
  const int m = min(gcnt[bid], GCAP);
  const int t = threadIdx.x;
  __shared__ float s_red[4];

  float a0 = 0.f, a1 = 0.f, a2 = 0.f, a3 = 0.f, a4 = 0.f, a5 = 0.f, a6 = 0.f, a7 = 0.f;
  int i = 0;
  for (; i + 8 <= m; i += 8) {
    a0 += feats[(size_t)list[i + 0] * DIM + t];
    a1 += feats[(size_t)list[i + 1] * DIM + t];
    a2 += feats[(size_t)list[i + 2] * DIM + t];
    a3 += feats[(size_t)list[i + 3] * DIM + t];
    a4 += feats[(size_t)list[i + 4] * DIM + t];
    a5 += feats[(size_t)list[i + 5] * DIM + t];
    a6 += feats[(size_t)list[i + 6] * DIM + t];
    a7 += feats[(size_t)list[i + 7] * DIM + t];
  }
  for (; i < m; i++) a0 += feats[(size_t)list[i] * DIM + t];
  const float sum = ((a0 + a1) + (a2 + a3)) + ((a4 + a5) + (a6 + a7));
  const float mean = sum / fmaxf((float)m, 1.0f);
  if (!side) mean_out[(size_t)c * DIM + t] = mean;

  float ss = mean * mean;
  #pragma unroll
  for (int o = 1; o < 64; o <<= 1) ss += __shfl_xor(ss, o);
  if ((t & 63) == 0) s_red[t >> 6] = ss;
  __syncthreads();
  const float tot = s_red[0] + s_red[1] + s_red[2] + s_red[3];
  const float innv = 1.0f / fmaxf(sqrtf(tot), 1e-12f);
  const float p = mean * innv;
  (side ? tpn : spn)[(size_t)c * DIM + t] = p;
  if (!side) {
    // fp8 tiled layout: byte = (c>>4)*4096 + (t>>6)*1024 + ((t>>3)&3)*256
    //                        + (c&15)*16 + ((t>>5)&1)*8 + (t&7)
    size_t off = (size_t)(c >> 4) * 4096 + (size_t)(t >> 6) * 1024
               + (size_t)((t >> 3) & 3) * 256 + (size_t)(c & 15) * 16
               + (size_t)((t >> 5) & 1) * 8 + (t & 7);
    unsigned q = CVTPK(p, p, 0u, false);
    pbf8[off] = (unsigned char)(q & 0xffu);
  }
}

// ---------------- K2: structure matrices + struct loss (fp32, 64x64 tiles) -----
__global__ __launch_bounds__(256) void struct_kernel(
    const float* __restrict__ spn, const float* __restrict__ tpn,
    float* __restrict__ out_struct, float* __restrict__ acc) {
  __shared__ float Sa[16][68], Sb[16][68], Ta[16][68], Tb[16][68];
  __shared__ float red[256];
  const int t = threadIdx.x;
  const int tx = t & 15, ty = t >> 4;
  const int i0 = blockIdx.y * 64, j0 = blockIdx.x * 64;
  float cs[4][4], cg[4][4];
  #pragma unroll
  for (int a = 0; a < 4; a++)
    #pragma unroll
    for (int b = 0; b < 4; b++) { cs[a][b] = 0.f; cg[a][b] = 0.f; }

  const int srow = t >> 2;
  const int skq = (t & 3) * 4;
  for (int k0 = 0; k0 < DIM; k0 += 16) {
    __syncthreads();
    {
      float4 z = make_float4(0.f, 0.f, 0.f, 0.f);
      int ra = i0 + srow, rb = j0 + srow;
      float4 va = (ra < NCLS) ? *(const float4*)(spn + (size_t)ra * DIM + k0 + skq) : z;
      float4 vb = (rb < NCLS) ? *(const float4*)(spn + (size_t)rb * DIM + k0 + skq) : z;
      float4 wa = (ra < NCLS) ? *(const float4*)(tpn + (size_t)ra * DIM + k0 + skq) : z;
      float4 wb = (rb < NCLS) ? *(const float4*)(tpn + (size_t)rb * DIM + k0 + skq) : z;
      Sa[skq+0][srow]=va.x; Sa[skq+1][srow]=va.y; Sa[skq+2][srow]=va.z; Sa[skq+3][srow]=va.w;
      Sb[skq+0][srow]=vb.x; Sb[skq+1][srow]=vb.y; Sb[skq+2][srow]=vb.z; Sb[skq+3][srow]=vb.w;
      Ta[skq+0][srow]=wa.x; Ta[skq+1][srow]=wa.y; Ta[skq+2][srow]=wa.z; Ta[skq+3][srow]=wa.w;
      Tb[skq+0][srow]=wb.x; Tb[skq+1][srow]=wb.y; Tb[skq+2][srow]=wb.z; Tb[skq+3][srow]=wb.w;
    }
    __syncthreads();
    #pragma unroll
    for (int k = 0; k < 16; k++) {
      float a[4], b[4], c[4], d[4];
      *(float4*)a = *(const float4*)&Sa[k][ty * 4];
      *(float4*)b = *(const float4*)&Sb[k][tx * 4];
      *(float4*)c = *(const float4*)&Ta[k][ty * 4];
      *(float4*)d = *(const float4*)&Tb[k][tx * 4];
      #pragma unroll
      for (int ii = 0; ii < 4; ii++)
        #pragma unroll
        for (int jj = 0; jj < 4; jj++) {
          cs[ii][jj] = fmaf(a[ii], b[jj], cs[ii][jj]);
          cg[ii][jj] = fmaf(c[ii], d[jj], cg[ii][jj]);
        }
    }
  }
  float d2 = 0.f;
  #pragma unroll
  for (int ii = 0; ii < 4; ii++) {
    int gi = i0 + ty * 4 + ii;
    if (gi < NCLS) {
      #pragma unroll
      for (int jj = 0; jj < 4; jj++) {
        int gj = j0 + tx * 4 + jj;
        if (gj < NCLS) {
          out_struct[(size_t)gi * NCLS + gj] = cs[ii][jj];
          float df = cs[ii][jj] - cg[ii][jj];
          d2 += df * df;
        }
      }
    }
  }
  red[t] = d2;
  __syncthreads();
  for (int o = 128; o > 0; o >>= 1) { if (t < o) red[t] += red[t + o]; __syncthreads(); }
  if (t == 0) atomicAdd(acc, red[0]);
}

// ------- K3: contrastive loss — fp8 port of the proven R10 structure -----------
// rf=2, 2-phase dbuf, in-loop label (code/labD), no pn reads, (256,4) cap 64.
__global__ __launch_bounds__(256, 4) void contrast_kernel(
    const float* __restrict__ feats, const int* __restrict__ labels,
    const unsigned char* __restrict__ pbf8,
    float* __restrict__ acc_out, int N) {
  __shared__ __align__(16) unsigned char Bt[2][4096];  // 2 x 4KB fp8 tiles
  __shared__ float red[256];
  const int t = threadIdx.x;
  const int lane = t & 63;
  const int lx = lane & 15, lg = lane >> 4;
  const int row0 = blockIdx.x * 128 + (t >> 6) * 32;
  const float4 z4 = make_float4(0.f, 0.f, 0.f, 0.f);

  i64 af[2][8];              // 32 rows/wave, raw feats in e4m3
  float sclF[2][4];          // (1/(T*ln2))/||f|| per owned row
  float sSt[2][4], labD[2][4];
  int code[2][4];            // label's 16-col tile index if lx matches, else big

  #pragma unroll
  for (int rf = 0; rf < 2; rf++) {
    const int r = row0 + rf * 16 + lx;
    const bool v = r < N;
    const float* rp = feats + (size_t)r * DIM + (lg << 3);
    float n2 = 0.f;
    #pragma unroll
    for (int kf = 0; kf < 8; kf++) {
      float4 x = v ? *(const float4*)(rp + kf * 32)     : z4;
      float4 y = v ? *(const float4*)(rp + kf * 32 + 4) : z4;
      n2 += x.x*x.x + x.y*x.y + x.z*x.z + x.w*x.w
          + y.x*y.x + y.y*y.y + y.z*y.z + y.w*y.w;
      unsigned w0 = CVTPK(x.x, x.y, 0u, false);
      w0 = CVTPK(x.z, x.w, w0, true);
      unsigned w1 = CVTPK(y.x, y.y, 0u, false);
      w1 = CVTPK(y.z, y.w, w1, true);
      af[rf][kf] = (i64)(((u64)w1 << 32) | (u64)w0);
    }
    n2 += __shfl_xor(n2, 16);
    n2 += __shfl_xor(n2, 32);
    const float sw = SCLF / fmaxf(sqrtf(n2), 1e-12f);
    #pragma unroll
    for (int reg = 0; reg < 4; reg++) {
      sclF[rf][reg] = __shfl(sw, (lg << 2) | reg);
      const int row = row0 + rf * 16 + (lg << 2) + reg;
      const int lb = (row < N) ? labels[row] : -1;
      code[rf][reg] = (lb >= 0 && (lb & 15) == lx) ? (lb >> 4) : 0x7fff;
      sSt[rf][reg] = 0.f;
      labD[rf][reg] = 0.f;
    }
  }

  // stage a 16-col fp8 tile (4KB): one gload_lds16 per thread, block-linear
  #define STAGE(cf_, buf_)                                                      \
    {                                                                           \
      const unsigned char* g0 = pbf8 + ((size_t)(cf_) << 12) + (t << 4);        \
      gload_lds16(g0, &Bt[buf_][t << 4]);                                       \
    }

  int cur = 0;
  STAGE(0, 0);
  __syncthreads();

  for (int cf = 0; cf < NT16; cf++) {
    if (cf < NT16 - 1) STAGE(cf + 1, cur ^ 1);

    const unsigned char* bb = &Bt[cur][(lg << 8) + (lx << 4)];
    f32x4 d0 = {0.f, 0.f, 0.f, 0.f};
    f32x4 d1 = {0.f, 0.f, 0.f, 0.f};
    #pragma unroll
    for (int q = 0; q < 4; q++) {
      int4 bq = *(const int4*)(bb + (q << 10));
      i64 b0 = ((const i64*)&bq)[0];
      i64 b1 = ((const i64*)&bq)[1];
      d0 = __builtin_amdgcn_mfma_f32_16x16x32_fp8_fp8(af[0][2*q],   b0, d0, 0, 0, 0);
      d1 = __builtin_amdgcn_mfma_f32_16x16x32_fp8_fp8(af[1][2*q],   b0, d1, 0, 0, 0);
      d0 = __builtin_amdgcn_mfma_f32_16x16x32_fp8_fp8(af[0][2*q+1], b1, d0, 0, 0, 0);
      d1 = __builtin_amdgcn_mfma_f32_16x16x32_fp8_fp8(af[1][2*q+1], b1, d1, 0, 0, 0);
    }
    #pragma unroll
    for (int reg = 0; reg < 4; reg++) {
      sSt[0][reg] += fexp2(fmaf(d0[reg], sclF[0][reg], -CP));
      sSt[1][reg] += fexp2(fmaf(d1[reg], sclF[1][reg], -CP));
      labD[0][reg] += (code[0][reg] == cf) ? d0[reg] : 0.f;
      labD[1][reg] += (code[1][reg] == cf) ? d1[reg] : 0.f;
    }
    __syncthreads();
    cur ^= 1;
  }

  float wl = 0.f;
  #pragma unroll
  for (int rf = 0; rf < 2; rf++)
    #pragma unroll
    for (int reg = 0; reg < 4; reg++) {
      float s = sSt[rf][reg], lb = labD[rf][reg];
      #pragma unroll
      for (int o = 1; o < 16; o <<= 1) { s += __shfl_xor(s, o); lb += __shfl_xor(lb, o); }
      const int row = row0 + rf * 16 + (lg << 2) + reg;
      if (lx == 0 && row < N)
        wl += logf(s - PADC) + CPLN2 - lb * sclF[rf][reg] * LN2;
    }

  red[t] = wl;
  __syncthreads();
  for (int o = 128; o > 0; o >>= 1) { if (t < o) red[t] += red[t + o]; __syncthreads(); }
  if (t == 0) atomicAdd(acc_out, red[0]);
}

// ---------------- K4: scalars ---------------------------------------------------
__global__ void final_kernel(const float* __restrict__ acc, float* __restrict__ out, int N) {
  out[0] = acc[0] * (1.0f / (float)(NCLS * NCLS));
  out[1] = acc[1] / (float)N;
}

extern "C" void kernel_launch(void* const* d_in, const int* in_sizes, int n_in,
                              void* d_out, int out_size, void* d_ws, size_t ws_size,
                              hipStream_t stream) {
  const float* src_feats  = (const float*)d_in[0];
  const int*   src_labels = (const int*)d_in[1];
  const float* tgt_feats  = (const float*)d_in[2];
  const int*   tgt_labels = (const int*)d_in[3];
  const int N = in_sizes[0] / DIM;

  // ws layout (floats):
  // [0,16)           acc: [0]=struct sq-sum, [1]=contrast sum
  // [16,256016)      src_pn
  // [256016,512016)  tgt_pn
  // [512016,577552)  pbf8: 64 tiles x 4096 bytes (fp8 e4m3, 1024 padded cols)
  // [643088,645088)  gcnt: 2000 ints
  float* ws = (float*)d_ws;
  float* acc    = ws;
  float* src_pn = ws + 16;
  float* tgt_pn = ws + 256016;
  unsigned char* pbf8 = (unsigned char*)(ws + 512016);
  int* gcnt = (int*)(ws + 643088);

  float* out_f      = (float*)d_out;
  float* out_protos = out_f + 2;
  float* out_struct = out_f + 2 + NCLS * DIM;
  // glist borrows the out_struct region (1M ints); struct_kernel overwrites it later
  int* glist = (int*)out_struct;

  hipMemsetAsync(acc, 0, 2 * sizeof(float), stream);
  hipMemsetAsync(gcnt, 0, 2 * NCLS * sizeof(int), stream);
  hipMemsetAsync(pbf8 + 62 * 4096, 0, 2 * 4096, stream);

  int sblocks = (2 * N + 255) / 256;
  scatter_kernel<<<sblocks, 256, 0, stream>>>(src_labels, tgt_labels, N, gcnt, glist);

  proto_kernel<<<2 * NCLS, 256, 0, stream>>>(src_feats, tgt_feats, gcnt, glist,
                                             out_protos, src_pn, tgt_pn, pbf8);

  dim3 sgrid(16, 16);
  struct_kernel<<<sgrid, 256, 0, stream>>>(src_pn, tgt_pn, out_struct, acc);

  int cblocks = (N + 127) / 128;
  contrast_kernel<<<cblocks, 256, 0, stream>>>(src_feats, src_labels, pbf8, acc + 1, N);

  final_kernel<<<1, 1, 0, stream>>>(acc, out_f, N);
}

// Round 15
// 395.648 us; speedup vs baseline: 1.7539x; 1.0345x over previous
//
#include <hip/hip_runtime.h>
#include <hip/hip_fp8.h>

#define NCLS 1000
#define DIM 256
#define GCAP 500
#define NT16 64                    // 64 tiles of 16 cols over 1024 padded cols
#define SCLF 20.609930f            // 1/(0.07*ln2)
#define CP 23.0f
#define CPLN2 15.94238515f         // 23*ln2
#define LN2 0.69314718056f
#define PADC 2.86102294921875e-06f // 24 * 2^-23 (pad-column contribution)

typedef __attribute__((ext_vector_type(4))) float f32x4;
typedef long long i64;
typedef unsigned long long u64;

#if defined(__has_builtin) && __has_builtin(__builtin_amdgcn_cvt_pk_fp8_f32)
#define CVTPK(a, b, old, hi) __builtin_amdgcn_cvt_pk_fp8_f32((a), (b), (old), (hi))
#else
__device__ __forceinline__ unsigned cvtpk_sw(float a, float b, unsigned old, bool hi) {
  unsigned lo8 = __hip_cvt_float_to_fp8(a, __HIP_SATFINITE, __HIP_E4M3);
  unsigned hi8 = __hip_cvt_float_to_fp8(b, __HIP_SATFINITE, __HIP_E4M3);
  unsigned pk = lo8 | (hi8 << 8);
  return hi ? ((old & 0xffffu) | (pk << 16)) : ((old & 0xffff0000u) | pk);
}
#define CVTPK(a, b, old, hi) cvtpk_sw((a), (b), (old), (hi))
#endif

__device__ __forceinline__ float fexp2(float x) {
#if __has_builtin(__builtin_amdgcn_exp2f)
  return __builtin_amdgcn_exp2f(x);
#else
  return exp2f(x);
#endif
}

// ---------------- K0: scatter rows into per-class lists ------------------------
__global__ __launch_bounds__(256) void scatter_kernel(
    const int* __restrict__ sl, const int* __restrict__ tl, int N,
    int* __restrict__ gcnt, int* __restrict__ glist) {
  const int i = blockIdx.x * 256 + threadIdx.x;
  if (i >= 2 * N) return;
  const int side = (i >= N) ? 1 : 0;
  const int r = i - side * N;
  const int c = (side ? tl : sl)[r];
  const int bin = side * NCLS + c;
  const int slot = atomicAdd(gcnt + bin, 1);
  if (slot < GCAP) glist[(size_t)bin * GCAP + slot] = r;
}

// ---------------- K1: per-class gather + mean + normalize ----------------------
__global__ __launch_bounds__(256) void proto_kernel(
    const float* __restrict__ sf, const float* __restrict__ tf,
    const int* __restrict__ gcnt, const int* __restrict__ glist,
    float* __restrict__ mean_out, float* __restrict__ spn, float* __restrict__ tpn,
    unsigned char* __restrict__ pbf8) {
  const int bid = blockIdx.x;
  const int side = (bid >= NCLS) ? 1 : 0;
  const int c = bid - side * NCLS;
  const float* feats = side ? tf : sf;
  const int* list = glist + (size_t)bid * GCAP;
  const int m = min(gcnt[bid], GCAP);
  const int t = threadIdx.x;
  __shared__ float s_red[4];

  float a0 = 0.f, a1 = 0.f, a2 = 0.f, a3 = 0.f, a4 = 0.f, a5 = 0.f, a6 = 0.f, a7 = 0.f;
  int i = 0;
  for (; i + 8 <= m; i += 8) {
    a0 += feats[(size_t)list[i + 0] * DIM + t];
    a1 += feats[(size_t)list[i + 1] * DIM + t];
    a2 += feats[(size_t)list[i + 2] * DIM + t];
    a3 += feats[(size_t)list[i + 3] * DIM + t];
    a4 += feats[(size_t)list[i + 4] * DIM + t];
    a5 += feats[(size_t)list[i + 5] * DIM + t];
    a6 += feats[(size_t)list[i + 6] * DIM + t];
    a7 += feats[(size_t)list[i + 7] * DIM + t];
  }
  for (; i < m; i++) a0 += feats[(size_t)list[i] * DIM + t];
  const float sum = ((a0 + a1) + (a2 + a3)) + ((a4 + a5) + (a6 + a7));
  const float mean = sum / fmaxf((float)m, 1.0f);
  if (!side) mean_out[(size_t)c * DIM + t] = mean;

  float ss = mean * mean;
  #pragma unroll
  for (int o = 1; o < 64; o <<= 1) ss += __shfl_xor(ss, o);
  if ((t & 63) == 0) s_red[t >> 6] = ss;
  __syncthreads();
  const float tot = s_red[0] + s_red[1] + s_red[2] + s_red[3];
  const float innv = 1.0f / fmaxf(sqrtf(tot), 1e-12f);
  const float p = mean * innv;
  (side ? tpn : spn)[(size_t)c * DIM + t] = p;
  if (!side) {
    // fp8 tiled layout: byte = (c>>4)*4096 + (t>>6)*1024 + ((t>>3)&3)*256
    //                        + (c&15)*16 + ((t>>5)&1)*8 + (t&7)
    size_t off = (size_t)(c >> 4) * 4096 + (size_t)(t >> 6) * 1024
               + (size_t)((t >> 3) & 3) * 256 + (size_t)(c & 15) * 16
               + (size_t)((t >> 5) & 1) * 8 + (t & 7);
    unsigned q = CVTPK(p, p, 0u, false);
    pbf8[off] = (unsigned char)(q & 0xffu);
  }
}

// ---------------- K2: structure matrices + struct loss (fp32, 64x64 tiles) -----
__global__ __launch_bounds__(256) void struct_kernel(
    const float* __restrict__ spn, const float* __restrict__ tpn,
    float* __restrict__ out_struct, float* __restrict__ acc) {
  __shared__ float Sa[16][68], Sb[16][68], Ta[16][68], Tb[16][68];
  __shared__ float red[256];
  const int t = threadIdx.x;
  const int tx = t & 15, ty = t >> 4;
  const int i0 = blockIdx.y * 64, j0 = blockIdx.x * 64;
  float cs[4][4], cg[4][4];
  #pragma unroll
  for (int a = 0; a < 4; a++)
    #pragma unroll
    for (int b = 0; b < 4; b++) { cs[a][b] = 0.f; cg[a][b] = 0.f; }

  const int srow = t >> 2;
  const int skq = (t & 3) * 4;
  for (int k0 = 0; k0 < DIM; k0 += 16) {
    __syncthreads();
    {
      float4 z = make_float4(0.f, 0.f, 0.f, 0.f);
      int ra = i0 + srow, rb = j0 + srow;
      float4 va = (ra < NCLS) ? *(const float4*)(spn + (size_t)ra * DIM + k0 + skq) : z;
      float4 vb = (rb < NCLS) ? *(const float4*)(spn + (size_t)rb * DIM + k0 + skq) : z;
      float4 wa = (ra < NCLS) ? *(const float4*)(tpn + (size_t)ra * DIM + k0 + skq) : z;
      float4 wb = (rb < NCLS) ? *(const float4*)(tpn + (size_t)rb * DIM + k0 + skq) : z;
      Sa[skq+0][srow]=va.x; Sa[skq+1][srow]=va.y; Sa[skq+2][srow]=va.z; Sa[skq+3][srow]=va.w;
      Sb[skq+0][srow]=vb.x; Sb[skq+1][srow]=vb.y; Sb[skq+2][srow]=vb.z; Sb[skq+3][srow]=vb.w;
      Ta[skq+0][srow]=wa.x; Ta[skq+1][srow]=wa.y; Ta[skq+2][srow]=wa.z; Ta[skq+3][srow]=wa.w;
      Tb[skq+0][srow]=wb.x; Tb[skq+1][srow]=wb.y; Tb[skq+2][srow]=wb.z; Tb[skq+3][srow]=wb.w;
    }
    __syncthreads();
    #pragma unroll
    for (int k = 0; k < 16; k++) {
      float a[4], b[4], c[4], d[4];
      *(float4*)a = *(const float4*)&Sa[k][ty * 4];
      *(float4*)b = *(const float4*)&Sb[k][tx * 4];
      *(float4*)c = *(const float4*)&Ta[k][ty * 4];
      *(float4*)d = *(const float4*)&Tb[k][tx * 4];
      #pragma unroll
      for (int ii = 0; ii < 4; ii++)
        #pragma unroll
        for (int jj = 0; jj < 4; jj++) {
          cs[ii][jj] = fmaf(a[ii], b[jj], cs[ii][jj]);
          cg[ii][jj] = fmaf(c[ii], d[jj], cg[ii][jj]);
        }
    }
  }
  float d2 = 0.f;
  #pragma unroll
  for (int ii = 0; ii < 4; ii++) {
    int gi = i0 + ty * 4 + ii;
    if (gi < NCLS) {
      #pragma unroll
      for (int jj = 0; jj < 4; jj++) {
        int gj = j0 + tx * 4 + jj;
        if (gj < NCLS) {
          out_struct[(size_t)gi * NCLS + gj] = cs[ii][jj];
          float df = cs[ii][jj] - cg[ii][jj];
          d2 += df * df;
        }
      }
    }
  }
  red[t] = d2;
  __syncthreads();
  for (int o = 128; o > 0; o >>= 1) { if (t < o) red[t] += red[t + o]; __syncthreads(); }
  if (t == 0) atomicAdd(acc, red[0]);
}

// ------- K3: contrastive loss — fp8 MFMA, register-dbuf B, no LDS/barriers -----
// 4 independent waves x 32 rows per block; each wave self-paced streams the
// 256KB fp8 B through registers (L2-resident). In-loop label scheme (no pn
// reads -> no spill). Per-wave atomic into 64 partial bins.
__global__ __launch_bounds__(256, 2) void contrast_kernel(
    const float* __restrict__ feats, const int* __restrict__ labels,
    const unsigned char* __restrict__ pbf8,
    float* __restrict__ accp, int N) {
  const int t = threadIdx.x;
  const int lane = t & 63;
  const int lx = lane & 15, lg = lane >> 4;
  const int row0 = blockIdx.x * 128 + (t >> 6) * 32;
  const float4 z4 = make_float4(0.f, 0.f, 0.f, 0.f);

  i64 af[2][8];              // 32 rows/wave, raw feats in e4m3
  float sclF[2][4];          // (1/(T*ln2))/||f|| per owned row
  float sSt[2][4], labD[2][4];
  int code[2][4];            // label's 16-col tile index if lx matches, else big

  #pragma unroll
  for (int rf = 0; rf < 2; rf++) {
    const int r = row0 + rf * 16 + lx;
    const bool v = r < N;
    const float* rp = feats + (size_t)r * DIM + (lg << 3);
    float n2 = 0.f;
    #pragma unroll
    for (int kf = 0; kf < 8; kf++) {
      float4 x = v ? *(const float4*)(rp + kf * 32)     : z4;
      float4 y = v ? *(const float4*)(rp + kf * 32 + 4) : z4;
      n2 += x.x*x.x + x.y*x.y + x.z*x.z + x.w*x.w
          + y.x*y.x + y.y*y.y + y.z*y.z + y.w*y.w;
      unsigned w0 = CVTPK(x.x, x.y, 0u, false);
      w0 = CVTPK(x.z, x.w, w0, true);
      unsigned w1 = CVTPK(y.x, y.y, 0u, false);
      w1 = CVTPK(y.z, y.w, w1, true);
      af[rf][kf] = (i64)(((u64)w1 << 32) | (u64)w0);
    }
    n2 += __shfl_xor(n2, 16);
    n2 += __shfl_xor(n2, 32);
    const float sw = SCLF / fmaxf(sqrtf(n2), 1e-12f);
    #pragma unroll
    for (int reg = 0; reg < 4; reg++) {
      sclF[rf][reg] = __shfl(sw, (lg << 2) | reg);
      const int row = row0 + rf * 16 + (lg << 2) + reg;
      const int lb = (row < N) ? labels[row] : -1;
      code[rf][reg] = (lb >= 0 && (lb & 15) == lx) ? (lb >> 4) : 0x7fff;
      sSt[rf][reg] = 0.f;
      labD[rf][reg] = 0.f;
    }
  }

  // B fragments direct from L2: per tile cf, 4 x int4, wave-private
  const unsigned char* bbase = pbf8 + (lg << 8) + (lx << 4);
  int4 bA[4], bB[4];

  #define LOADB(dst_, cf_)                                                      \
    {                                                                           \
      const int4* gp = (const int4*)(bbase + ((size_t)(cf_) << 12));            \
      _Pragma("unroll")                                                         \
      for (int q = 0; q < 4; q++) dst_[q] = gp[q << 6];                         \
    }

  #define COMPUTE(buf_, g_)                                                     \
    {                                                                           \
      f32x4 d0 = {0.f, 0.f, 0.f, 0.f};                                          \
      f32x4 d1 = {0.f, 0.f, 0.f, 0.f};                                          \
      _Pragma("unroll")                                                         \
      for (int q = 0; q < 4; q++) {                                             \
        i64 b0 = ((const i64*)&buf_[q])[0];                                     \
        i64 b1 = ((const i64*)&buf_[q])[1];                                     \
        d0 = __builtin_amdgcn_mfma_f32_16x16x32_fp8_fp8(af[0][2*q],   b0, d0, 0, 0, 0); \
        d1 = __builtin_amdgcn_mfma_f32_16x16x32_fp8_fp8(af[1][2*q],   b0, d1, 0, 0, 0); \
        d0 = __builtin_amdgcn_mfma_f32_16x16x32_fp8_fp8(af[0][2*q+1], b1, d0, 0, 0, 0); \
        d1 = __builtin_amdgcn_mfma_f32_16x16x32_fp8_fp8(af[1][2*q+1], b1, d1, 0, 0, 0); \
      }                                                                         \
      _Pragma("unroll")                                                         \
      for (int reg = 0; reg < 4; reg++) {                                       \
        sSt[0][reg] += fexp2(fmaf(d0[reg], sclF[0][reg], -CP));                 \
        sSt[1][reg] += fexp2(fmaf(d1[reg], sclF[1][reg], -CP));                 \
        labD[0][reg] += (code[0][reg] == (g_)) ? d0[reg] : 0.f;                 \
        labD[1][reg] += (code[1][reg] == (g_)) ? d1[reg] : 0.f;                 \
      }                                                                         \
    }

  LOADB(bA, 0);
  for (int cf = 0; cf < NT16; cf += 2) {
    LOADB(bB, cf + 1);
    COMPUTE(bA, cf);
    if (cf + 2 < NT16) LOADB(bA, cf + 2);
    COMPUTE(bB, cf + 1);
  }

  float wl = 0.f;
  #pragma unroll
  for (int rf = 0; rf < 2; rf++)
    #pragma unroll
    for (int reg = 0; reg < 4; reg++) {
      float s = sSt[rf][reg], lb = labD[rf][reg];
      #pragma unroll
      for (int o = 1; o < 16; o <<= 1) { s += __shfl_xor(s, o); lb += __shfl_xor(lb, o); }
      const int row = row0 + rf * 16 + (lg << 2) + reg;
      if (lx == 0 && row < N)
        wl += logf(s - PADC) + CPLN2 - lb * sclF[rf][reg] * LN2;
    }

  // full-wave reduce (wl nonzero only on lx==0 lanes), one atomic per wave
  #pragma unroll
  for (int o = 1; o < 64; o <<= 1) wl += __shfl_xor(wl, o);
  if (lane == 0) atomicAdd(accp + (blockIdx.x & 63), wl);
}

// ---------------- K4: scalars ---------------------------------------------------
__global__ void final_kernel(const float* __restrict__ acc,
                             const float* __restrict__ accp,
                             float* __restrict__ out, int N) {
  float c = 0.f;
  for (int i = 0; i < 64; i++) c += accp[i];
  out[0] = acc[0] * (1.0f / (float)(NCLS * NCLS));
  out[1] = c / (float)N;
}

extern "C" void kernel_launch(void* const* d_in, const int* in_sizes, int n_in,
                              void* d_out, int out_size, void* d_ws, size_t ws_size,
                              hipStream_t stream) {
  const float* src_feats  = (const float*)d_in[0];
  const int*   src_labels = (const int*)d_in[1];
  const float* tgt_feats  = (const float*)d_in[2];
  const int*   tgt_labels = (const int*)d_in[3];
  const int N = in_sizes[0] / DIM;

  // ws layout (floats):
  // [0,16)           acc: [0]=struct sq-sum
  // [16,256016)      src_pn
  // [256016,512016)  tgt_pn
  // [512016,577552)  pbf8: 64 tiles x 4096 bytes (fp8 e4m3, 1024 padded cols)
  // [643088,645088)  gcnt: 2000 ints
  // [645088,645152)  accp: 64 contrast partial bins
  float* ws = (float*)d_ws;
  float* acc    = ws;
  float* src_pn = ws + 16;
  float* tgt_pn = ws + 256016;
  unsigned char* pbf8 = (unsigned char*)(ws + 512016);
  int* gcnt = (int*)(ws + 643088);
  float* accp = ws + 645088;

  float* out_f      = (float*)d_out;
  float* out_protos = out_f + 2;
  float* out_struct = out_f + 2 + NCLS * DIM;
  // glist borrows the out_struct region (1M ints); struct_kernel overwrites it later
  int* glist = (int*)out_struct;

  hipMemsetAsync(acc, 0, 2 * sizeof(float), stream);
  hipMemsetAsync(gcnt, 0, 2 * NCLS * sizeof(int), stream);
  hipMemsetAsync(accp, 0, 64 * sizeof(float), stream);
  hipMemsetAsync(pbf8 + 62 * 4096, 0, 2 * 4096, stream);

  int sblocks = (2 * N + 255) / 256;
  scatter_kernel<<<sblocks, 256, 0, stream>>>(src_labels, tgt_labels, N, gcnt, glist);

  proto_kernel<<<2 * NCLS, 256, 0, stream>>>(src_feats, tgt_feats, gcnt, glist,
                                             out_protos, src_pn, tgt_pn, pbf8);

  dim3 sgrid(16, 16);
  struct_kernel<<<sgrid, 256, 0, stream>>>(src_pn, tgt_pn, out_struct, acc);

  int cblocks = (N + 127) / 128;
  contrast_kernel<<<cblocks, 256, 0, stream>>>(src_feats, src_labels, pbf8, accp, N);

  final_kernel<<<1, 1, 0, stream>>>(acc, accp, out_f, N);
}

// Round 16
// 361.754 us; speedup vs baseline: 1.9182x; 1.0937x over previous
//
#include <hip/hip_runtime.h>
#include <hip/hip_fp8.h>

#define NCLS 1000
#define DIM 256
#define GCAP 500
#define NT16 64                    // 64 tiles of 16 cols over 1024 padded cols
#define SCLF 20.609930f            // 1/(0.07*ln2)
#define CP 23.0f
#define CPLN2 15.94238515f         // 23*ln2
#define LN2 0.69314718056f
#define PADC 2.86102294921875e-06f // 24 * 2^-23 (pad-column contribution)

typedef __attribute__((ext_vector_type(4))) float f32x4;
typedef long long i64;
typedef unsigned long long u64;

#if defined(__has_builtin) && __has_builtin(__builtin_amdgcn_cvt_pk_fp8_f32)
#define CVTPK(a, b, old, hi) __builtin_amdgcn_cvt_pk_fp8_f32((a), (b), (old), (hi))
#else
__device__ __forceinline__ unsigned cvtpk_sw(float a, float b, unsigned old, bool hi) {
  unsigned lo8 = __hip_cvt_float_to_fp8(a, __HIP_SATFINITE, __HIP_E4M3);
  unsigned hi8 = __hip_cvt_float_to_fp8(b, __HIP_SATFINITE, __HIP_E4M3);
  unsigned pk = lo8 | (hi8 << 8);
  return hi ? ((old & 0xffffu) | (pk << 16)) : ((old & 0xffff0000u) | pk);
}
#define CVTPK(a, b, old, hi) cvtpk_sw((a), (b), (old), (hi))
#endif

__device__ __forceinline__ float fexp2(float x) {
#if __has_builtin(__builtin_amdgcn_exp2f)
  return __builtin_amdgcn_exp2f(x);
#else
  return exp2f(x);
#endif
}

// ---------------- K0: scatter rows into per-class lists ------------------------
__global__ __launch_bounds__(256) void scatter_kernel(
    const int* __restrict__ sl, const int* __restrict__ tl, int N,
    int* __restrict__ gcnt, int* __restrict__ glist) {
  const int i = blockIdx.x * 256 + threadIdx.x;
  if (i >= 2 * N) return;
  const int side = (i >= N) ? 1 : 0;
  const int r = i - side * N;
  const int c = (side ? tl : sl)[r];
  const int bin = side * NCLS + c;
  const int slot = atomicAdd(gcnt + bin, 1);
  if (slot < GCAP) glist[(size_t)bin * GCAP + slot] = r;
}

// ---------------- K1: per-class gather + mean + normalize ----------------------
// tgt classes first (bid<NCLS), src last -> src feats stay L3-warm for contrast.
__global__ __launch_bounds__(256) void proto_kernel(
    const float* __restrict__ sf, const float* __restrict__ tf,
    const int* __restrict__ gcnt, const int* __restrict__ glist,
    float* __restrict__ mean_out, float* __restrict__ spn, float* __restrict__ tpn,
    unsigned char* __restrict__ pbf8) {
  const int bid = blockIdx.x;
  const int side = (bid < NCLS) ? 1 : 0;          // 1 = tgt (processed first)
  const int c = side ? bid : (bid - NCLS);
  const int bin = side * NCLS + c;
  const float* feats = side ? tf : sf;
  const int* list = glist + (size_t)bin * GCAP;
  const int m = min(gcnt[bin], GCAP);
  const int t = threadIdx.x;
  __shared__ float s_red[4];

  float a0 = 0.f, a1 = 0.f, a2 = 0.f, a3 = 0.f, a4 = 0.f, a5 = 0.f, a6 = 0.f, a7 = 0.f;
  int i = 0;
  for (; i + 8 <= m; i += 8) {
    a0 += feats[(size_t)list[i + 0] * DIM + t];
    a1 += feats[(size_t)list[i + 1] * DIM + t];
    a2 += feats[(size_t)list[i + 2] * DIM + t];
    a3 += feats[(size_t)list[i + 3] * DIM + t];
    a4 += feats[(size_t)list[i + 4] * DIM + t];
    a5 += feats[(size_t)list[i + 5] * DIM + t];
    a6 += feats[(size_t)list[i + 6] * DIM + t];
    a7 += feats[(size_t)list[i + 7] * DIM + t];
  }
  for (; i < m; i++) a0 += feats[(size_t)list[i] * DIM + t];
  const float sum = ((a0 + a1) + (a2 + a3)) + ((a4 + a5) + (a6 + a7));
  const float mean = sum / fmaxf((float)m, 1.0f);
  if (!side) mean_out[(size_t)c * DIM + t] = mean;

  float ss = mean * mean;
  #pragma unroll
  for (int o = 1; o < 64; o <<= 1) ss += __shfl_xor(ss, o);
  if ((t & 63) == 0) s_red[t >> 6] = ss;
  __syncthreads();
  const float tot = s_red[0] + s_red[1] + s_red[2] + s_red[3];
  const float innv = 1.0f / fmaxf(sqrtf(tot), 1e-12f);
  const float p = mean * innv;
  (side ? tpn : spn)[(size_t)c * DIM + t] = p;
  if (!side) {
    // fp8 tiled layout: byte = (c>>4)*4096 + (t>>6)*1024 + ((t>>3)&3)*256
    //                        + (c&15)*16 + ((t>>5)&1)*8 + (t&7)
    size_t off = (size_t)(c >> 4) * 4096 + (size_t)(t >> 6) * 1024
               + (size_t)((t >> 3) & 3) * 256 + (size_t)(c & 15) * 16
               + (size_t)((t >> 5) & 1) * 8 + (t & 7);
    unsigned q = CVTPK(p, p, 0u, false);
    pbf8[off] = (unsigned char)(q & 0xffu);
  }
}

// ------- K2: FUSED struct + contrast (contrast blocks first) -------------------
__global__ __launch_bounds__(256, 2) void fused_kernel(
    const float* __restrict__ feats, const int* __restrict__ labels,
    const unsigned char* __restrict__ pbf8, float* __restrict__ accp,
    const float* __restrict__ spn, const float* __restrict__ tpn,
    float* __restrict__ out_struct, float* __restrict__ acc,
    int N, int cblocks) {
  const int bid = blockIdx.x;
  const int t = threadIdx.x;

  if (bid >= cblocks) {
    // ================= struct path (256 blocks, 64x64 tiles) ==================
    const int sbid = bid - cblocks;
    __shared__ float Sa[16][68], Sb[16][68], Ta[16][68], Tb[16][68];
    __shared__ float red[256];
    const int tx = t & 15, ty = t >> 4;
    const int i0 = (sbid >> 4) * 64, j0 = (sbid & 15) * 64;
    float cs[4][4], cg[4][4];
    #pragma unroll
    for (int a = 0; a < 4; a++)
      #pragma unroll
      for (int b = 0; b < 4; b++) { cs[a][b] = 0.f; cg[a][b] = 0.f; }

    const int srow = t >> 2;
    const int skq = (t & 3) * 4;
    for (int k0 = 0; k0 < DIM; k0 += 16) {
      __syncthreads();
      {
        float4 z = make_float4(0.f, 0.f, 0.f, 0.f);
        int ra = i0 + srow, rb = j0 + srow;
        float4 va = (ra < NCLS) ? *(const float4*)(spn + (size_t)ra * DIM + k0 + skq) : z;
        float4 vb = (rb < NCLS) ? *(const float4*)(spn + (size_t)rb * DIM + k0 + skq) : z;
        float4 wa = (ra < NCLS) ? *(const float4*)(tpn + (size_t)ra * DIM + k0 + skq) : z;
        float4 wb = (rb < NCLS) ? *(const float4*)(tpn + (size_t)rb * DIM + k0 + skq) : z;
        Sa[skq+0][srow]=va.x; Sa[skq+1][srow]=va.y; Sa[skq+2][srow]=va.z; Sa[skq+3][srow]=va.w;
        Sb[skq+0][srow]=vb.x; Sb[skq+1][srow]=vb.y; Sb[skq+2][srow]=vb.z; Sb[skq+3][srow]=vb.w;
        Ta[skq+0][srow]=wa.x; Ta[skq+1][srow]=wa.y; Ta[skq+2][srow]=wa.z; Ta[skq+3][srow]=wa.w;
        Tb[skq+0][srow]=wb.x; Tb[skq+1][srow]=wb.y; Tb[skq+2][srow]=wb.z; Tb[skq+3][srow]=wb.w;
      }
      __syncthreads();
      #pragma unroll
      for (int k = 0; k < 16; k++) {
        float a[4], b[4], c[4], d[4];
        *(float4*)a = *(const float4*)&Sa[k][ty * 4];
        *(float4*)b = *(const float4*)&Sb[k][tx * 4];
        *(float4*)c = *(const float4*)&Ta[k][ty * 4];
        *(float4*)d = *(const float4*)&Tb[k][tx * 4];
        #pragma unroll
        for (int ii = 0; ii < 4; ii++)
          #pragma unroll
          for (int jj = 0; jj < 4; jj++) {
            cs[ii][jj] = fmaf(a[ii], b[jj], cs[ii][jj]);
            cg[ii][jj] = fmaf(c[ii], d[jj], cg[ii][jj]);
          }
      }
    }
    float d2 = 0.f;
    #pragma unroll
    for (int ii = 0; ii < 4; ii++) {
      int gi = i0 + ty * 4 + ii;
      if (gi < NCLS) {
        #pragma unroll
        for (int jj = 0; jj < 4; jj++) {
          int gj = j0 + tx * 4 + jj;
          if (gj < NCLS) {
            out_struct[(size_t)gi * NCLS + gj] = cs[ii][jj];
            float df = cs[ii][jj] - cg[ii][jj];
            d2 += df * df;
          }
        }
      }
    }
    red[t] = d2;
    __syncthreads();
    for (int o = 128; o > 0; o >>= 1) { if (t < o) red[t] += red[t + o]; __syncthreads(); }
    if (t == 0) atomicAdd(acc, red[0]);
    return;
  }

  // ================= contrast path (no LDS, no barriers) ======================
  const int lane = t & 63;
  const int lx = lane & 15, lg = lane >> 4;
  const int row0 = bid * 128 + (t >> 6) * 32;
  const float4 z4 = make_float4(0.f, 0.f, 0.f, 0.f);

  i64 af[2][8];              // 32 rows/wave, raw feats in e4m3
  float sclF[2][4];          // (1/(T*ln2))/||f|| per owned row
  float sSt[2][4], labD[2][4];
  int codeP[2];              // 4 x 8-bit label tile codes per rf (255 = none)

  #pragma unroll
  for (int rf = 0; rf < 2; rf++) {
    const int r = row0 + rf * 16 + lx;
    const bool v = r < N;
    const float* rp = feats + (size_t)r * DIM + (lg << 3);
    float n2 = 0.f;
    #pragma unroll
    for (int kf = 0; kf < 8; kf++) {
      float4 x = v ? *(const float4*)(rp + kf * 32)     : z4;
      float4 y = v ? *(const float4*)(rp + kf * 32 + 4) : z4;
      n2 += x.x*x.x + x.y*x.y + x.z*x.z + x.w*x.w
          + y.x*y.x + y.y*y.y + y.z*y.z + y.w*y.w;
      unsigned w0 = CVTPK(x.x, x.y, 0u, false);
      w0 = CVTPK(x.z, x.w, w0, true);
      unsigned w1 = CVTPK(y.x, y.y, 0u, false);
      w1 = CVTPK(y.z, y.w, w1, true);
      af[rf][kf] = (i64)(((u64)w1 << 32) | (u64)w0);
    }
    n2 += __shfl_xor(n2, 16);
    n2 += __shfl_xor(n2, 32);
    const float sw = SCLF / fmaxf(sqrtf(n2), 1e-12f);
    int pc = 0;
    #pragma unroll
    for (int reg = 0; reg < 4; reg++) {
      sclF[rf][reg] = __shfl(sw, (lg << 2) | reg);
      const int row = row0 + rf * 16 + (lg << 2) + reg;
      const int lb = (row < N) ? labels[row] : -1;
      const int tc = (lb >= 0 && (lb & 15) == lx) ? (lb >> 4) : 255;
      pc |= tc << (reg * 8);
      sSt[rf][reg] = 0.f;
      labD[rf][reg] = 0.f;
    }
    codeP[rf] = pc;
  }

  // B fragments direct from L2: per tile cf, 4 x int4, wave-private, ring-of-3
  const unsigned char* bbase = pbf8 + (lg << 8) + (lx << 4);
  int4 b0[4], b1[4], b2[4];

  #define LOADB(dst_, cf_)                                                      \
    {                                                                           \
      const int4* gp = (const int4*)(bbase + ((size_t)(cf_) << 12));            \
      _Pragma("unroll")                                                         \
      for (int q = 0; q < 4; q++) dst_[q] = gp[q << 6];                         \
    }

  #define COMPUTE(buf_, g_)                                                     \
    {                                                                           \
      f32x4 d0 = {0.f, 0.f, 0.f, 0.f};                                          \
      f32x4 d1 = {0.f, 0.f, 0.f, 0.f};                                          \
      _Pragma("unroll")                                                         \
      for (int q = 0; q < 4; q++) {                                             \
        i64 e0 = ((const i64*)&buf_[q])[0];                                     \
        i64 e1 = ((const i64*)&buf_[q])[1];                                     \
        d0 = __builtin_amdgcn_mfma_f32_16x16x32_fp8_fp8(af[0][2*q],   e0, d0, 0, 0, 0); \
        d1 = __builtin_amdgcn_mfma_f32_16x16x32_fp8_fp8(af[1][2*q],   e0, d1, 0, 0, 0); \
        d0 = __builtin_amdgcn_mfma_f32_16x16x32_fp8_fp8(af[0][2*q+1], e1, d0, 0, 0, 0); \
        d1 = __builtin_amdgcn_mfma_f32_16x16x32_fp8_fp8(af[1][2*q+1], e1, d1, 0, 0, 0); \
      }                                                                         \
      _Pragma("unroll")                                                         \
      for (int reg = 0; reg < 4; reg++) {                                       \
        sSt[0][reg] += fexp2(fmaf(d0[reg], sclF[0][reg], -CP));                 \
        sSt[1][reg] += fexp2(fmaf(d1[reg], sclF[1][reg], -CP));                 \
        labD[0][reg] += (((codeP[0] >> (reg * 8)) & 255) == (g_)) ? d0[reg] : 0.f; \
        labD[1][reg] += (((codeP[1] >> (reg * 8)) & 255) == (g_)) ? d1[reg] : 0.f; \
      }                                                                         \
    }

  LOADB(b0, 0);
  LOADB(b1, 1);
  int cf = 0;
  for (; cf + 3 <= NT16; cf += 3) {
    LOADB(b2, cf + 2);
    COMPUTE(b0, cf);
    if (cf + 3 < NT16) LOADB(b0, cf + 3);
    COMPUTE(b1, cf + 1);
    if (cf + 4 < NT16) LOADB(b1, cf + 4);
    COMPUTE(b2, cf + 2);
  }
  if (cf < NT16) COMPUTE(b0, cf);   // NT16 = 64 = 21*3 + 1 -> tile 63 in b0

  float wl = 0.f;
  #pragma unroll
  for (int rf = 0; rf < 2; rf++)
    #pragma unroll
    for (int reg = 0; reg < 4; reg++) {
      float s = sSt[rf][reg], lb = labD[rf][reg];
      #pragma unroll
      for (int o = 1; o < 16; o <<= 1) { s += __shfl_xor(s, o); lb += __shfl_xor(lb, o); }
      const int row = row0 + rf * 16 + (lg << 2) + reg;
      if (lx == 0 && row < N)
        wl += logf(s - PADC) + CPLN2 - lb * sclF[rf][reg] * LN2;
    }

  // full-wave reduce (wl nonzero only on lx==0 lanes), one atomic per wave
  #pragma unroll
  for (int o = 1; o < 64; o <<= 1) wl += __shfl_xor(wl, o);
  if (lane == 0) atomicAdd(accp + (bid & 63), wl);
}

// ---------------- K4: scalars ---------------------------------------------------
__global__ void final_kernel(const float* __restrict__ acc,
                             const float* __restrict__ accp,
                             float* __restrict__ out, int N) {
  float c = 0.f;
  for (int i = 0; i < 64; i++) c += accp[i];
  out[0] = acc[0] * (1.0f / (float)(NCLS * NCLS));
  out[1] = c / (float)N;
}

extern "C" void kernel_launch(void* const* d_in, const int* in_sizes, int n_in,
                              void* d_out, int out_size, void* d_ws, size_t ws_size,
                              hipStream_t stream) {
  const float* src_feats  = (const float*)d_in[0];
  const int*   src_labels = (const int*)d_in[1];
  const float* tgt_feats  = (const float*)d_in[2];
  const int*   tgt_labels = (const int*)d_in[3];
  const int N = in_sizes[0] / DIM;

  // ws layout (floats):
  // [0,16)           acc: [0]=struct sq-sum
  // [16,256016)      src_pn
  // [256016,512016)  tgt_pn
  // [512016,577552)  pbf8: 64 tiles x 4096 bytes (fp8 e4m3, 1024 padded cols)
  // [643088,645088)  gcnt: 2000 ints
  // [645088,645152)  accp: 64 contrast partial bins
  float* ws = (float*)d_ws;
  float* acc    = ws;
  float* src_pn = ws + 16;
  float* tgt_pn = ws + 256016;
  unsigned char* pbf8 = (unsigned char*)(ws + 512016);
  int* gcnt = (int*)(ws + 643088);
  float* accp = ws + 645088;

  float* out_f      = (float*)d_out;
  float* out_protos = out_f + 2;
  float* out_struct = out_f + 2 + NCLS * DIM;
  // glist borrows the out_struct region (1M ints); fused struct path overwrites later
  int* glist = (int*)out_struct;

  hipMemsetAsync(acc, 0, 2 * sizeof(float), stream);
  hipMemsetAsync(gcnt, 0, 2 * NCLS * sizeof(int), stream);
  hipMemsetAsync(accp, 0, 64 * sizeof(float), stream);
  hipMemsetAsync(pbf8 + 62 * 4096, 0, 2 * 4096, stream);

  int sblocks = (2 * N + 255) / 256;
  scatter_kernel<<<sblocks, 256, 0, stream>>>(src_labels, tgt_labels, N, gcnt, glist);

  proto_kernel<<<2 * NCLS, 256, 0, stream>>>(src_feats, tgt_feats, gcnt, glist,
                                             out_protos, src_pn, tgt_pn, pbf8);

  int cblocks = (N + 127) / 128;
  fused_kernel<<<cblocks + 256, 256, 0, stream>>>(
      src_feats, src_labels, pbf8, accp, src_pn, tgt_pn, out_struct, acc, N, cblocks);

  final_kernel<<<1, 1, 0, stream>>>(acc, accp, out_f, N);
}